// Round 1
// baseline (174.657 us; speedup 1.0000x reference)
//
#include <hip/hip_runtime.h>

#define NN 50000
#define BB 32
#define KK 32

// Kernel 1: compute augmented features h[n][b] = (f0,f1,f2, f0^2+f1^2+f2^2)
// f[b,n,j] = leaky_relu( sum_e (x[b,n]+emb[n,e]) * W[j,e] + bias[j], 0.2 )
__global__ __launch_bounds__(256) void compute_f_kernel(
    const float* __restrict__ x,      // (B,N)
    const float* __restrict__ emb,    // (N,6)
    const float* __restrict__ W,      // (3,6)
    const float* __restrict__ bias,   // (3,)
    float4* __restrict__ h)           // (N,B)
{
    int t = blockIdx.x * blockDim.x + threadIdx.x;
    int n = t >> 5;
    int b = t & 31;
    if (n >= NN) return;

    float xv = x[b * NN + n];
    float e0 = emb[n * 6 + 0], e1 = emb[n * 6 + 1], e2 = emb[n * 6 + 2];
    float e3 = emb[n * 6 + 3], e4 = emb[n * 6 + 4], e5 = emb[n * 6 + 5];

    float a[3];
#pragma unroll
    for (int j = 0; j < 3; ++j) {
        float w0 = W[j * 6 + 0], w1 = W[j * 6 + 1], w2 = W[j * 6 + 2];
        float w3 = W[j * 6 + 3], w4 = W[j * 6 + 4], w5 = W[j * 6 + 5];
        float acc = bias[j]
            + (xv + e0) * w0 + (xv + e1) * w1 + (xv + e2) * w2
            + (xv + e3) * w3 + (xv + e4) * w4 + (xv + e5) * w5;
        a[j] = acc > 0.f ? acc : 0.2f * acc;
    }
    float s = a[0] * a[0] + a[1] * a[1] + a[2] * a[2];
    h[n * BB + b] = make_float4(a[0], a[1], a[2], s);
}

// Kernel 2: one block per node n (256 threads = 4 waves = 8 subgroups of 32).
// Each 32-lane subgroup handles one neighbor k at a time (4 iterations),
// lane b = lane&31 covers the batch dim. d2 = s_n + s_m - 2*dot(f_n,f_m).
__global__ __launch_bounds__(256) void gather_kernel(
    const float4* __restrict__ h,     // (N,B)
    const int* __restrict__ nbr,      // (N,K)
    float* __restrict__ out)          // (N,K)
{
    __shared__ float4 fn_sh[BB];
    __shared__ int nbr_sh[KK];

    int n = blockIdx.x;
    int t = threadIdx.x;

    if (t < KK) nbr_sh[t] = nbr[n * KK + t];
    else if (t >= 64 && t < 64 + BB) fn_sh[t - 64] = h[n * BB + (t - 64)];
    __syncthreads();

    int lane = t & 63;
    int wave = t >> 6;
    int sub  = lane >> 5;       // 0/1 within wave
    int b    = lane & 31;
    int kg   = wave * 2 + sub;  // 0..7

    float4 hn = fn_sh[b];

#pragma unroll
    for (int i = 0; i < 4; ++i) {
        int k = kg + i * 8;
        int m = nbr_sh[k];
        int mc = (m < 0) ? 0 : m;
        float4 hm = h[(size_t)mc * BB + b];
        float dot = hn.x * hm.x + hn.y * hm.y + hn.z * hm.z;
        float d2  = hn.w + hm.w - 2.f * dot;
        float v   = __expf(-d2);
        v += __shfl_down(v, 16, 32);
        v += __shfl_down(v, 8, 32);
        v += __shfl_down(v, 4, 32);
        v += __shfl_down(v, 2, 32);
        v += __shfl_down(v, 1, 32);
        if (b == 0) out[n * KK + k] = (m < 0) ? 0.f : v * (1.0f / 32.0f);
    }
}

extern "C" void kernel_launch(void* const* d_in, const int* in_sizes, int n_in,
                              void* d_out, int out_size, void* d_ws, size_t ws_size,
                              hipStream_t stream) {
    const float* x    = (const float*)d_in[0];
    const float* emb  = (const float*)d_in[1];
    const float* W    = (const float*)d_in[2];
    const float* bias = (const float*)d_in[3];
    const int*   nbr  = (const int*)d_in[4];
    float* out = (float*)d_out;
    float4* h  = (float4*)d_ws;   // needs N*B*16 = 25.6 MB

    int total = NN * BB;
    compute_f_kernel<<<(total + 255) / 256, 256, 0, stream>>>(x, emb, W, bias, h);
    gather_kernel<<<NN, 256, 0, stream>>>(h, nbr, out);
}

// Round 2
// 159.906 us; speedup vs baseline: 1.0922x; 1.0922x over previous
//
#include <hip/hip_runtime.h>

#define NN 50000
#define BB 32
#define KK 32

typedef __attribute__((ext_vector_type(4))) _Float16 half4;

// Kernel 1: h2[n][b] = half4(f0,f1,f2,0) where
// f[j] = leaky_relu( x[b,n]*ws[j] + g[n,j] , 0.2 ),
// ws[j] = sum_e W[j,e],  g[n,j] = sum_e emb[n,e]*W[j,e] + bias[j].
// (e = x + emb broadcasts x over E, so the einsum factors.)
__global__ __launch_bounds__(256) void compute_f_kernel(
    const float* __restrict__ x,      // (B,N)
    const float* __restrict__ emb,    // (N,6)
    const float* __restrict__ W,      // (3,6)
    const float* __restrict__ bias,   // (3,)
    half4* __restrict__ h)            // (N,B) fp16
{
    __shared__ float xs[BB][257];     // +1 pad: transpose reads conflict-free
    __shared__ float gs[256][3];

    const int n0 = blockIdx.x * 256;
    const int t  = threadIdx.x;

    // Stage x tile (32 b-rows x 256 n-cols), coalesced 256B per wave-read.
#pragma unroll
    for (int j = 0; j < 32; ++j) {
        int idx = j * 256 + t;
        int b = idx >> 8, c = idx & 255;
        int n = n0 + c;
        xs[b][c] = (n < NN) ? x[b * NN + n] : 0.f;
    }

    // Per-node g[n][j] (one thread per node).
    {
        int n = n0 + t;
        float e[6];
#pragma unroll
        for (int q = 0; q < 6; ++q) e[q] = (n < NN) ? emb[n * 6 + q] : 0.f;
#pragma unroll
        for (int j = 0; j < 3; ++j) {
            float g = bias[j];
#pragma unroll
            for (int q = 0; q < 6; ++q) g += e[q] * W[j * 6 + q];
            gs[t][j] = g;
        }
    }
    __syncthreads();

    float ws[3];
#pragma unroll
    for (int j = 0; j < 3; ++j) {
        float s = 0.f;
#pragma unroll
        for (int q = 0; q < 6; ++q) s += W[j * 6 + q];
        ws[j] = s;
    }

    const int b = t & 31;
    const int grp = t >> 5;           // 8 n-groups of 32 lanes
    for (int i = 0; i < 32; ++i) {
        int nl = grp + i * 8;
        int n = n0 + nl;
        if (n >= NN) break;           // uniform within subgroup
        float xv = xs[b][nl];         // stride 257 -> all banks distinct
        float f0 = gs[nl][0] + xv * ws[0];
        float f1 = gs[nl][1] + xv * ws[1];
        float f2 = gs[nl][2] + xv * ws[2];
        f0 = f0 > 0.f ? f0 : 0.2f * f0;
        f1 = f1 > 0.f ? f1 : 0.2f * f1;
        f2 = f2 > 0.f ? f2 : 0.2f * f2;
        half4 r;
        r.x = (_Float16)f0; r.y = (_Float16)f1; r.z = (_Float16)f2;
        r.w = (_Float16)0.f;
        h[n * BB + b] = r;            // lanes b=0..31 -> 256B contiguous
    }
}

// Kernel 2: one block per node n. 8 subgroups of 32 lanes; subgroup handles
// neighbor k, lane b covers batch. d2 computed directly from fp16 deltas
// (NOT via the norm trick -- avoids fp16 cancellation).
__global__ __launch_bounds__(256) void gather_kernel(
    const half4* __restrict__ h,      // (N,B) fp16
    const int* __restrict__ nbr,      // (N,K)
    float* __restrict__ out)          // (N,K)
{
    __shared__ float4 fn_sh[BB];
    __shared__ int nbr_sh[KK];

    const int n = blockIdx.x;
    const int t = threadIdx.x;

    if (t < KK) nbr_sh[t] = nbr[n * KK + t];
    else if (t >= 64 && t < 64 + BB) {
        half4 v = h[n * BB + (t - 64)];
        fn_sh[t - 64] = make_float4((float)v.x, (float)v.y, (float)v.z, 0.f);
    }
    __syncthreads();

    const int lane = t & 63;
    const int wave = t >> 6;
    const int sub  = lane >> 5;
    const int b    = lane & 31;
    const int kg   = wave * 2 + sub;  // 0..7

    float4 hn = fn_sh[b];

#pragma unroll
    for (int i = 0; i < 4; ++i) {
        int k = kg + i * 8;
        int m = nbr_sh[k];
        int mc = (m < 0) ? 0 : m;
        half4 hm = h[(size_t)mc * BB + b];   // 8B/lane, 256B/row coalesced
        float dx = hn.x - (float)hm.x;
        float dy = hn.y - (float)hm.y;
        float dz = hn.z - (float)hm.z;
        float v  = __expf(-(dx * dx + dy * dy + dz * dz));
        v += __shfl_down(v, 16, 32);
        v += __shfl_down(v, 8, 32);
        v += __shfl_down(v, 4, 32);
        v += __shfl_down(v, 2, 32);
        v += __shfl_down(v, 1, 32);
        if (b == 0) out[n * KK + k] = (m < 0) ? 0.f : v * (1.0f / 32.0f);
    }
}

extern "C" void kernel_launch(void* const* d_in, const int* in_sizes, int n_in,
                              void* d_out, int out_size, void* d_ws, size_t ws_size,
                              hipStream_t stream) {
    const float* x    = (const float*)d_in[0];
    const float* emb  = (const float*)d_in[1];
    const float* W    = (const float*)d_in[2];
    const float* bias = (const float*)d_in[3];
    const int*   nbr  = (const int*)d_in[4];
    float* out = (float*)d_out;
    half4* h   = (half4*)d_ws;        // N*B*8 = 12.8 MB

    compute_f_kernel<<<(NN + 255) / 256, 256, 0, stream>>>(x, emb, W, bias, h);
    gather_kernel<<<NN, 256, 0, stream>>>(h, nbr, out);
}

// Round 3
// 152.246 us; speedup vs baseline: 1.1472x; 1.0503x over previous
//
#include <hip/hip_runtime.h>

#define NN 50000
#define BB 32
#define KK 32
#define TN 32   // nodes per block in compute_f

typedef __attribute__((ext_vector_type(4))) _Float16 half4;

// Kernel 1: h[n][b] = half4(f0,f1,f2,0),
// f[j] = leaky_relu( x[b,n]*ws[j] + g[n,j], 0.2 ),
// ws[j] = sum_e W[j,e], g[n,j] = sum_e emb[n,e]*W[j,e] + bias[j].
// 32-node tile per block -> 1563 blocks (R2's 256-node tile gave only 196
// blocks on 256 CUs: latency-bound at ~75us. Parallelism over elegance.)
__global__ __launch_bounds__(256) void compute_f_kernel(
    const float* __restrict__ x,      // (B,N)
    const float* __restrict__ emb,    // (N,6)
    const float* __restrict__ W,      // (3,6)
    const float* __restrict__ bias,   // (3,)
    half4* __restrict__ h)            // (N,B) fp16
{
    __shared__ float xs[BB][TN + 1];  // +1 pad: transpose read conflict-free

    const int n0 = blockIdx.x * TN;
    const int t  = threadIdx.x;

    // Stage x tile (32 b-rows x 32 n-cols): 4 loads/thread,
    // each 32-lane group reads 128B contiguous.
#pragma unroll
    for (int j = 0; j < 4; ++j) {
        int idx = j * 256 + t;        // 0..1023
        int b = idx >> 5, c = idx & 31;
        int n = n0 + c;
        xs[b][c] = (n < NN) ? x[b * NN + n] : 0.f;
    }
    __syncthreads();

    float ws[3];
#pragma unroll
    for (int j = 0; j < 3; ++j) {
        float s = 0.f;
#pragma unroll
        for (int q = 0; q < 6; ++q) s += W[j * 6 + q];
        ws[j] = s;
    }

    const int b   = t & 31;
    const int sub = t >> 5;           // 8 subgroups of 32 lanes
#pragma unroll
    for (int i = 0; i < 4; ++i) {
        int nl = i * 8 + sub;
        int n  = n0 + nl;
        if (n < NN) {
            // g[j]: same emb addresses across the 32-lane subgroup (broadcast).
            float e[6];
#pragma unroll
            for (int q = 0; q < 6; ++q) e[q] = emb[n * 6 + q];
            float xv = xs[b][nl];     // stride 33 -> conflict-free
            half4 r;
            float f[3];
#pragma unroll
            for (int j = 0; j < 3; ++j) {
                float g = bias[j];
#pragma unroll
                for (int q = 0; q < 6; ++q) g += e[q] * W[j * 6 + q];
                float v = g + xv * ws[j];
                f[j] = v > 0.f ? v : 0.2f * v;
            }
            r.x = (_Float16)f[0]; r.y = (_Float16)f[1];
            r.z = (_Float16)f[2]; r.w = (_Float16)0.f;
            h[n * BB + b] = r;        // 32 lanes -> 256B contiguous
        }
    }
}

// Kernel 2: one block per node n. 8 subgroups of 32 lanes; subgroup handles
// neighbor k, lane b covers batch. d2 computed directly from fp16 deltas
// (NOT via the norm trick -- avoids fp16 cancellation).
__global__ __launch_bounds__(256) void gather_kernel(
    const half4* __restrict__ h,      // (N,B) fp16
    const int* __restrict__ nbr,      // (N,K)
    float* __restrict__ out)          // (N,K)
{
    __shared__ float4 fn_sh[BB];
    __shared__ int nbr_sh[KK];

    const int n = blockIdx.x;
    const int t = threadIdx.x;

    if (t < KK) nbr_sh[t] = nbr[n * KK + t];
    else if (t >= 64 && t < 64 + BB) {
        half4 v = h[n * BB + (t - 64)];
        fn_sh[t - 64] = make_float4((float)v.x, (float)v.y, (float)v.z, 0.f);
    }
    __syncthreads();

    const int lane = t & 63;
    const int wave = t >> 6;
    const int sub  = lane >> 5;
    const int b    = lane & 31;
    const int kg   = wave * 2 + sub;  // 0..7

    float4 hn = fn_sh[b];

#pragma unroll
    for (int i = 0; i < 4; ++i) {
        int k = kg + i * 8;
        int m = nbr_sh[k];
        int mc = (m < 0) ? 0 : m;
        half4 hm = h[(size_t)mc * BB + b];   // 8B/lane, 256B/row coalesced
        float dx = hn.x - (float)hm.x;
        float dy = hn.y - (float)hm.y;
        float dz = hn.z - (float)hm.z;
        float v  = __expf(-(dx * dx + dy * dy + dz * dz));
        v += __shfl_down(v, 16, 32);
        v += __shfl_down(v, 8, 32);
        v += __shfl_down(v, 4, 32);
        v += __shfl_down(v, 2, 32);
        v += __shfl_down(v, 1, 32);
        if (b == 0) out[n * KK + k] = (m < 0) ? 0.f : v * (1.0f / 32.0f);
    }
}

extern "C" void kernel_launch(void* const* d_in, const int* in_sizes, int n_in,
                              void* d_out, int out_size, void* d_ws, size_t ws_size,
                              hipStream_t stream) {
    const float* x    = (const float*)d_in[0];
    const float* emb  = (const float*)d_in[1];
    const float* W    = (const float*)d_in[2];
    const float* bias = (const float*)d_in[3];
    const int*   nbr  = (const int*)d_in[4];
    float* out = (float*)d_out;
    half4* h   = (half4*)d_ws;        // N*B*8 = 12.8 MB

    compute_f_kernel<<<(NN + TN - 1) / TN, 256, 0, stream>>>(x, emb, W, bias, h);
    gather_kernel<<<NN, 256, 0, stream>>>(h, nbr, out);
}

// Round 4
// 122.650 us; speedup vs baseline: 1.4240x; 1.2413x over previous
//
#include <hip/hip_runtime.h>

#define NN 50000
#define BB 32
#define KK 32
#define TN 64   // nodes per block in prep kernel

typedef __attribute__((ext_vector_type(2))) _Float16 half2_t;

// Prep kernel: instead of materializing f (B*N*F), store only what gather
// needs to RECOMPUTE f on the fly:
//   xT[n][b2] = half2(x[2*b2, n], x[2*b2+1, n])   (fp16, 64 B per node row)
//   g4[n]     = (g0, g1, g2, 0) fp32, g[j] = sum_e emb[n,e]*W[j,e] + bias[j]
// f[b,n,j] = leaky_relu(x[b,n]*ws[j] + g[n,j]),  ws[j] = sum_e W[j,e].
// Working set for the random gather: 3.2 MB + 0.8 MB = 4 MB (fits L2).
__global__ __launch_bounds__(256) void prep_kernel(
    const float* __restrict__ x,      // (B,N)
    const float* __restrict__ emb,    // (N,6)
    const float* __restrict__ W,      // (3,6)
    const float* __restrict__ bias,   // (3,)
    half2_t* __restrict__ xT,         // (N,16) half2
    float4* __restrict__ g4)          // (N)
{
    __shared__ float xs[BB][TN + 1];  // +1 pad: transpose read conflict-free

    const int n0 = blockIdx.x * TN;
    const int t  = threadIdx.x;

    // Stage x tile (32 b-rows x 64 n-cols): each wave reads 256B contiguous.
#pragma unroll
    for (int j = 0; j < 8; ++j) {
        int idx = j * 256 + t;        // 0..2047
        int r = idx >> 6, c = idx & 63;
        int n = n0 + c;
        xs[r][c] = (n < NN) ? x[r * NN + n] : 0.f;
    }
    __syncthreads();

    // 4 slots/thread: slot -> (node nl, half-pair b2). b2 fast-varying so
    // 16-lane groups write 64B contiguous.
#pragma unroll
    for (int it = 0; it < 4; ++it) {
        int slot = it * 256 + t;      // 0..1023
        int nl = slot >> 4, b2 = slot & 15;
        int n = n0 + nl;
        if (n < NN) {
            float x0 = xs[2 * b2][nl];     // banks (2*b2+nl)%32: distinct
            float x1 = xs[2 * b2 + 1][nl];
            half2_t p;
            p.x = (_Float16)x0; p.y = (_Float16)x1;
            xT[n * 16 + b2] = p;
            if (b2 == 0) {
                float e[6];
#pragma unroll
                for (int q = 0; q < 6; ++q) e[q] = emb[n * 6 + q];
                float g[3];
#pragma unroll
                for (int j = 0; j < 3; ++j) {
                    float s = bias[j];
#pragma unroll
                    for (int q = 0; q < 6; ++q) s += e[q] * W[j * 6 + q];
                    g[j] = s;
                }
                g4[n] = make_float4(g[0], g[1], g[2], 0.f);
            }
        }
    }
}

// Gather: one block per node n. 16 subgroups of 16 lanes; subgroup handles
// neighbor k (2 iterations), lane b2 covers batch pairs (2 b's per lane).
// f recomputed from xT (fp16) + g4 (fp32) -- 64B + 16B per neighbor instead
// of the old 256B materialized-f row.
__global__ __launch_bounds__(256) void gather_kernel(
    const half2_t* __restrict__ xT,   // (N,16)
    const float4* __restrict__ g4,    // (N)
    const float* __restrict__ W,      // (3,6)
    const int* __restrict__ nbr,      // (N,K)
    float* __restrict__ out)          // (N,K)
{
    __shared__ int nbr_sh[KK];

    const int n = blockIdx.x;
    const int t = threadIdx.x;

    if (t < KK) nbr_sh[t] = nbr[n * KK + t];
    __syncthreads();

    float ws[3];
#pragma unroll
    for (int j = 0; j < 3; ++j) {
        float s = 0.f;
#pragma unroll
        for (int q = 0; q < 6; ++q) s += W[j * 6 + q];
        ws[j] = s;
    }

    const int lane = t & 63;
    const int wave = t >> 6;
    const int sub  = lane >> 4;       // 0..3 within wave
    const int b2   = lane & 15;
    const int kg   = wave * 4 + sub;  // 0..15

    // Center features for this lane's two b values.
    half2_t xn2 = xT[n * 16 + b2];
    float4 gn = g4[n];
    float gnj[3] = {gn.x, gn.y, gn.z};
    float xa = (float)xn2.x, xb = (float)xn2.y;
    float fa[3], fb[3];
#pragma unroll
    for (int j = 0; j < 3; ++j) {
        float u = xa * ws[j] + gnj[j];
        fa[j] = u > 0.f ? u : 0.2f * u;
        float v = xb * ws[j] + gnj[j];
        fb[j] = v > 0.f ? v : 0.2f * v;
    }

#pragma unroll
    for (int i = 0; i < 2; ++i) {
        int k = kg + i * 16;
        int m = nbr_sh[k];
        int mc = (m < 0) ? 0 : m;
        half2_t xm2 = xT[(size_t)mc * 16 + b2];   // 64B/row, coalesced
        float4 gm = g4[mc];                        // broadcast, 16B
        float gmj[3] = {gm.x, gm.y, gm.z};
        float ya = (float)xm2.x, yb = (float)xm2.y;
        float da = 0.f, db = 0.f;
#pragma unroll
        for (int j = 0; j < 3; ++j) {
            float u = ya * ws[j] + gmj[j];
            u = u > 0.f ? u : 0.2f * u;
            float du = fa[j] - u;
            da += du * du;
            float v = yb * ws[j] + gmj[j];
            v = v > 0.f ? v : 0.2f * v;
            float dv = fb[j] - v;
            db += dv * dv;
        }
        float v = __expf(-da) + __expf(-db);      // theta=0.5 -> exp(-d2)
        v += __shfl_down(v, 8, 16);
        v += __shfl_down(v, 4, 16);
        v += __shfl_down(v, 2, 16);
        v += __shfl_down(v, 1, 16);
        if (b2 == 0) out[n * KK + k] = (m < 0) ? 0.f : v * (1.0f / 32.0f);
    }
}

extern "C" void kernel_launch(void* const* d_in, const int* in_sizes, int n_in,
                              void* d_out, int out_size, void* d_ws, size_t ws_size,
                              hipStream_t stream) {
    const float* x    = (const float*)d_in[0];
    const float* emb  = (const float*)d_in[1];
    const float* W    = (const float*)d_in[2];
    const float* bias = (const float*)d_in[3];
    const int*   nbr  = (const int*)d_in[4];
    float* out = (float*)d_out;

    half2_t* xT = (half2_t*)d_ws;                       // N*16*4 = 3.2 MB
    float4*  g4 = (float4*)((char*)d_ws + NN * 16 * sizeof(half2_t)); // 0.8 MB

    prep_kernel<<<(NN + TN - 1) / TN, 256, 0, stream>>>(x, emb, W, bias, xT, g4);
    gather_kernel<<<NN, 256, 0, stream>>>(xT, g4, W, nbr, out);
}

// Round 5
// 121.362 us; speedup vs baseline: 1.4391x; 1.0106x over previous
//
#include <hip/hip_runtime.h>

#define NN 50000
#define BB 32
#define KK 32
#define TN 64   // nodes per block in prep kernel

typedef __attribute__((ext_vector_type(2))) _Float16 half2_t;
typedef __attribute__((ext_vector_type(8))) _Float16 half8_t;

// Prep: store what gather needs to RECOMPUTE f on the fly, in fp16:
//   xT[n][b2] = half2(x[2b2,n], x[2b2+1,n])         (64 B/node row)
//   gh[n]     = half8: dwords = (g0,g0),(g1,g1),(g2,g2),(0,0)  (16 B/node)
// g[j] = sum_e emb[n,e]*W[j,e] + bias[j]; pre-duplicated halves so gather's
// packed-fp16 math needs ZERO register massage after the dwordx4 load.
// Random-gather working set: 3.2 + 0.8 = 4 MB (L2-resident).
__global__ __launch_bounds__(256) void prep_kernel(
    const float* __restrict__ x,      // (B,N)
    const float* __restrict__ emb,    // (N,6)
    const float* __restrict__ W,      // (3,6)
    const float* __restrict__ bias,   // (3,)
    half2_t* __restrict__ xT,         // (N,16)
    half8_t* __restrict__ gh)         // (N)
{
    __shared__ float xs[BB][TN + 1];  // +1 pad: transpose read conflict-free

    const int n0 = blockIdx.x * TN;
    const int t  = threadIdx.x;

#pragma unroll
    for (int j = 0; j < 8; ++j) {
        int idx = j * 256 + t;        // 0..2047
        int r = idx >> 6, c = idx & 63;
        int n = n0 + c;
        xs[r][c] = (n < NN) ? x[r * NN + n] : 0.f;
    }
    __syncthreads();

#pragma unroll
    for (int it = 0; it < 4; ++it) {
        int slot = it * 256 + t;      // 0..1023
        int nl = slot >> 4, b2 = slot & 15;
        int n = n0 + nl;
        if (n < NN) {
            half2_t p;
            p.x = (_Float16)xs[2 * b2][nl];     // banks 2*b2+nl: distinct
            p.y = (_Float16)xs[2 * b2 + 1][nl];
            xT[n * 16 + b2] = p;                // 16 lanes -> 64B contiguous
            if (b2 == 0) {
                float e[6];
#pragma unroll
                for (int q = 0; q < 6; ++q) e[q] = emb[n * 6 + q];
                half8_t gv;
#pragma unroll
                for (int j = 0; j < 3; ++j) {
                    float s = bias[j];
#pragma unroll
                    for (int q = 0; q < 6; ++q) s += e[q] * W[j * 6 + q];
                    gv[2 * j] = (_Float16)s;
                    gv[2 * j + 1] = (_Float16)s;
                }
                gv[6] = (_Float16)0.f; gv[7] = (_Float16)0.f;
                gh[n] = gv;
            }
        }
    }
}

// Gather: block per node n; 16 subgroups of 16 lanes; subgroup handles
// neighbor k (2 iters), lane b2 covers a batch PAIR. All per-b math is
// packed fp16 (v_pk_fma/v_pk_mul/v_pk_max): f = max(u, 0.2u), u = x*ws+g,
// d2 accumulated packed; f32 only at the two exps.
__global__ __launch_bounds__(256) void gather_kernel(
    const half2_t* __restrict__ xT,   // (N,16)
    const half8_t* __restrict__ gh,   // (N)
    const float* __restrict__ W,      // (3,6)
    const int* __restrict__ nbr,      // (N,K)
    float* __restrict__ out)          // (N,K)
{
    __shared__ int nbr_sh[KK];

    const int n = blockIdx.x;
    const int t = threadIdx.x;

    if (t < KK) nbr_sh[t] = nbr[n * KK + t];
    __syncthreads();

    // ws[j] = sum_e W[j,e], duplicated into both halves (uniform).
    half2_t ws2[3];
#pragma unroll
    for (int j = 0; j < 3; ++j) {
        float s = 0.f;
#pragma unroll
        for (int q = 0; q < 6; ++q) s += W[j * 6 + q];
        _Float16 h = (_Float16)s;
        ws2[j].x = h; ws2[j].y = h;
    }
    half2_t lk; lk.x = (_Float16)0.2f; lk.y = (_Float16)0.2f;

    const int lane = t & 63;
    const int wave = t >> 6;
    const int sub  = lane >> 4;       // 0..3
    const int b2   = lane & 15;
    const int kg   = wave * 4 + sub;  // 0..15

    // Center features (packed over the lane's two b values).
    half2_t xn2 = xT[n * 16 + b2];
    half8_t gn8 = gh[n];
    half2_t fn[3];
#pragma unroll
    for (int j = 0; j < 3; ++j) {
        half2_t g = __builtin_shufflevector(gn8, gn8, 0, 1);
        if (j == 1) g = __builtin_shufflevector(gn8, gn8, 2, 3);
        if (j == 2) g = __builtin_shufflevector(gn8, gn8, 4, 5);
        half2_t u = xn2 * ws2[j] + g;             // v_pk_fma_f16
        fn[j] = __builtin_elementwise_max(u, u * lk);
    }

#pragma unroll
    for (int i = 0; i < 2; ++i) {
        int k = kg + i * 16;
        int m = nbr_sh[k];
        int mc = (m < 0) ? 0 : m;
        half2_t xm2 = xT[mc * 16 + b2];           // 4B/lane, 64B/row coalesced
        half8_t gm8 = gh[mc];                     // one dwordx4, broadcast
        half2_t g0 = __builtin_shufflevector(gm8, gm8, 0, 1);
        half2_t g1 = __builtin_shufflevector(gm8, gm8, 2, 3);
        half2_t g2 = __builtin_shufflevector(gm8, gm8, 4, 5);

        half2_t acc; acc.x = (_Float16)0.f; acc.y = (_Float16)0.f;
        half2_t u, d;
        u = xm2 * ws2[0] + g0; u = __builtin_elementwise_max(u, u * lk);
        d = fn[0] - u; acc = d * d + acc;
        u = xm2 * ws2[1] + g1; u = __builtin_elementwise_max(u, u * lk);
        d = fn[1] - u; acc = d * d + acc;
        u = xm2 * ws2[2] + g2; u = __builtin_elementwise_max(u, u * lk);
        d = fn[2] - u; acc = d * d + acc;

        float v = __expf(-(float)acc.x) + __expf(-(float)acc.y);
        v += __shfl_down(v, 8, 16);
        v += __shfl_down(v, 4, 16);
        v += __shfl_down(v, 2, 16);
        v += __shfl_down(v, 1, 16);
        if (b2 == 0) out[n * KK + k] = (m < 0) ? 0.f : v * (1.0f / 32.0f);
    }
}

extern "C" void kernel_launch(void* const* d_in, const int* in_sizes, int n_in,
                              void* d_out, int out_size, void* d_ws, size_t ws_size,
                              hipStream_t stream) {
    const float* x    = (const float*)d_in[0];
    const float* emb  = (const float*)d_in[1];
    const float* W    = (const float*)d_in[2];
    const float* bias = (const float*)d_in[3];
    const int*   nbr  = (const int*)d_in[4];
    float* out = (float*)d_out;

    half2_t* xT = (half2_t*)d_ws;                              // 3.2 MB
    half8_t* gh = (half8_t*)((char*)d_ws + NN * 16 * sizeof(half2_t)); // 0.8 MB

    prep_kernel<<<(NN + TN - 1) / TN, 256, 0, stream>>>(x, emb, W, bias, xT, gh);
    gather_kernel<<<NN, 256, 0, stream>>>(xT, gh, W, nbr, out);
}

// Round 7
// 99.259 us; speedup vs baseline: 1.7596x; 1.2227x over previous
//
#include <hip/hip_runtime.h>

#define NN 50000
#define BB 32
#define KK 32
#define TN 64   // nodes per block in prep kernel
#define GN 8    // nodes per block in gather kernel (NN % GN == 0)

typedef __attribute__((ext_vector_type(2))) _Float16 half2_t;
typedef __attribute__((ext_vector_type(4))) _Float16 half4_t;
typedef __attribute__((ext_vector_type(8))) _Float16 half8_t;

// __builtin_shufflevector needs literal indices -> hand-unrolled extractors.
__device__ __forceinline__ half4_t g_dup0(half8_t v) {
    return __builtin_shufflevector(v, v, 0, 1, 0, 1);
}
__device__ __forceinline__ half4_t g_dup1(half8_t v) {
    return __builtin_shufflevector(v, v, 2, 3, 2, 3);
}
__device__ __forceinline__ half4_t g_dup2(half8_t v) {
    return __builtin_shufflevector(v, v, 4, 5, 4, 5);
}

// Prep: store what gather needs to RECOMPUTE f on the fly, in fp16:
//   xT[n][b2] = half2(x[2b2,n], x[2b2+1,n])         (64 B/node row)
//   gh[n]     = half8: dwords = (g0,g0),(g1,g1),(g2,g2),(0,0)  (16 B/node)
// g[j] = sum_e emb[n,e]*W[j,e] + bias[j]; duplicated halves so gather's
// packed-fp16 math needs no register massage after the dwordx4 load.
// Random-gather working set: 3.2 + 0.8 = 4 MB (L2-resident).
__global__ __launch_bounds__(256) void prep_kernel(
    const float* __restrict__ x,      // (B,N)
    const float* __restrict__ emb,    // (N,6)
    const float* __restrict__ W,      // (3,6)
    const float* __restrict__ bias,   // (3,)
    half2_t* __restrict__ xT,         // (N,16)
    half8_t* __restrict__ gh)         // (N)
{
    __shared__ float xs[BB][TN + 1];  // +1 pad: transpose read conflict-free

    const int n0 = blockIdx.x * TN;
    const int t  = threadIdx.x;

#pragma unroll
    for (int j = 0; j < 8; ++j) {
        int idx = j * 256 + t;        // 0..2047
        int r = idx >> 6, c = idx & 63;
        int n = n0 + c;
        xs[r][c] = (n < NN) ? x[r * NN + n] : 0.f;
    }
    __syncthreads();

#pragma unroll
    for (int it = 0; it < 4; ++it) {
        int slot = it * 256 + t;      // 0..1023
        int nl = slot >> 4, b2 = slot & 15;
        int n = n0 + nl;
        if (n < NN) {
            half2_t p;
            p.x = (_Float16)xs[2 * b2][nl];
            p.y = (_Float16)xs[2 * b2 + 1][nl];
            xT[n * 16 + b2] = p;                // 16 lanes -> 64B contiguous
            if (b2 == 0) {
                float e[6];
#pragma unroll
                for (int q = 0; q < 6; ++q) e[q] = emb[n * 6 + q];
                half8_t gv;
#pragma unroll
                for (int j = 0; j < 3; ++j) {
                    float s = bias[j];
#pragma unroll
                    for (int q = 0; q < 6; ++q) s += e[q] * W[j * 6 + q];
                    gv[2 * j] = (_Float16)s;
                    gv[2 * j + 1] = (_Float16)s;
                }
                gv[6] = (_Float16)0.f; gv[7] = (_Float16)0.f;
                gh[n] = gv;
            }
        }
    }
}

// Gather: block = 8 nodes (grid 6250). 32 subgroups of 8 lanes; subgroup
// sg owns node (sg>>2) and k-range (sg&3)*8..+7, lane l holds b = 4l..4l+3
// as one half4 (2 pk ops per vector op). fn lives in registers (computed
// once per subgroup); 8 fully-unrolled k-iterations give the compiler 8
// hoistable broadcast ds_reads of m and 16 independent global loads to
// pipeline. Preamble amortized over 256 pairs (R5: 32).
__global__ __launch_bounds__(256) void gather_kernel(
    const half4_t* __restrict__ xT4,  // (N,8) viewed as half4
    const half8_t* __restrict__ gh,   // (N)
    const float* __restrict__ W,      // (3,6)
    const int* __restrict__ nbr,      // (N,K)
    float* __restrict__ out)          // (N,K)
{
    __shared__ int nbr_sh[GN * KK];   // 8 nodes x 32 k

    const int t  = threadIdx.x;
    const int n0 = blockIdx.x * GN;

    nbr_sh[t] = nbr[n0 * KK + t];
    __syncthreads();

    // ws[j] = sum_e W[j,e], duplicated across half4.
    half4_t ws4[3];
#pragma unroll
    for (int j = 0; j < 3; ++j) {
        float s = 0.f;
#pragma unroll
        for (int q = 0; q < 6; ++q) s += W[j * 6 + q];
        _Float16 h = (_Float16)s;
        ws4[j].x = h; ws4[j].y = h; ws4[j].z = h; ws4[j].w = h;
    }
    half4_t lk;
    lk.x = (_Float16)0.2f; lk.y = (_Float16)0.2f;
    lk.z = (_Float16)0.2f; lk.w = (_Float16)0.2f;

    const int l  = t & 7;             // lane in subgroup
    const int sg = t >> 3;            // 0..31
    const int nl = sg >> 2;           // node local 0..7
    const int kg = (sg & 3) * 8;      // k base
    const int n  = n0 + nl;

    // Center features for this lane's 4 b's (registers, once per subgroup).
    half4_t xn4 = xT4[n * 8 + l];     // 8B/lane, 64B/row coalesced
    half8_t gn8 = gh[n];
    half4_t fn[3];
    {
        half4_t u0 = xn4 * ws4[0] + g_dup0(gn8);
        fn[0] = __builtin_elementwise_max(u0, u0 * lk);
        half4_t u1 = xn4 * ws4[1] + g_dup1(gn8);
        fn[1] = __builtin_elementwise_max(u1, u1 * lk);
        half4_t u2 = xn4 * ws4[2] + g_dup2(gn8);
        fn[2] = __builtin_elementwise_max(u2, u2 * lk);
    }

    const int mbase = nl * KK + kg;   // nbr_sh base for this subgroup

#pragma unroll
    for (int i = 0; i < 8; ++i) {
        int m  = nbr_sh[mbase + i];   // broadcast ds_read, imm offset
        int mc = m > 0 ? m : 0;
        half4_t xm4 = xT4[mc * 8 + l];          // 8B/lane
        half8_t gm8 = gh[mc];                   // 16B broadcast per subgroup

        half4_t acc;
        acc.x = (_Float16)0.f; acc.y = (_Float16)0.f;
        acc.z = (_Float16)0.f; acc.w = (_Float16)0.f;
        {
            half4_t u, d;
            u = xm4 * ws4[0] + g_dup0(gm8);
            u = __builtin_elementwise_max(u, u * lk);
            d = fn[0] - u; acc = d * d + acc;
            u = xm4 * ws4[1] + g_dup1(gm8);
            u = __builtin_elementwise_max(u, u * lk);
            d = fn[1] - u; acc = d * d + acc;
            u = xm4 * ws4[2] + g_dup2(gm8);
            u = __builtin_elementwise_max(u, u * lk);
            d = fn[2] - u; acc = d * d + acc;
        }
        float v = (__expf(-(float)acc.x) + __expf(-(float)acc.y))
                + (__expf(-(float)acc.z) + __expf(-(float)acc.w));
        v += __shfl_down(v, 4, 8);
        v += __shfl_down(v, 2, 8);
        v += __shfl_down(v, 1, 8);
        if (l == 0) out[n * KK + kg + i] = (m < 0) ? 0.f : v * (1.0f / 32.0f);
    }
}

extern "C" void kernel_launch(void* const* d_in, const int* in_sizes, int n_in,
                              void* d_out, int out_size, void* d_ws, size_t ws_size,
                              hipStream_t stream) {
    const float* x    = (const float*)d_in[0];
    const float* emb  = (const float*)d_in[1];
    const float* W    = (const float*)d_in[2];
    const float* bias = (const float*)d_in[3];
    const int*   nbr  = (const int*)d_in[4];
    float* out = (float*)d_out;

    half2_t* xT = (half2_t*)d_ws;                              // 3.2 MB
    half8_t* gh = (half8_t*)((char*)d_ws + NN * 16 * sizeof(half2_t)); // 0.8 MB

    prep_kernel<<<(NN + TN - 1) / TN, 256, 0, stream>>>(x, emb, W, bias, xT, gh);
    gather_kernel<<<NN / GN, 256, 0, stream>>>((const half4_t*)xT, gh, W, nbr, out);
}